// Round 4
// baseline (1348.171 us; speedup 1.0000x reference)
//
#include <hip/hip_runtime.h>
#include <hip/hip_bf16.h>

// DaGCN forward. Inputs f32 + int32; OUTPUT f32 (3 x [N,32] concat, reference dtype).
//
// Workspace (byte offsets):
//   [0, 6.4M)      sA  bf16 [N,64]     (phase2: xbuf bf16 [N,128] spans sA|sB)
//   [6.4M, 12.8M)  sB  bf16 [N,64]
//   [12.8M, 25.6M) y1  bf16 [N,128]    (phase2: s2 f32 [N,32])
//   [25.6M, 38.4M) aVA f32 [N,64]      (phase2: aL2_1 | aL2_2 f32 [N,32])
//   [38.4M, 51.2M) aVB f32 [N,64]
//   [51.2M, +200K) p1  f32 [N]
// Peak 51.4 MB (guarded).

#define NNODES 50000
#define NEDGES 800000

typedef __attribute__((ext_vector_type(4))) unsigned short ushort4v;

__device__ __forceinline__ float bf2f(unsigned short u) {
    return __uint_as_float(((unsigned int)u) << 16);
}
__device__ __forceinline__ unsigned short f2bf(float f) {
    __hip_bfloat16 h = __float2bfloat16(f);
    unsigned short u;
    __builtin_memcpy(&u, &h, 2);
    return u;
}
__device__ __forceinline__ float sigmoidf(float v) {
    return 1.f / (1.f + expf(-v));
}

// ---------------------------------------------------------------- GEMM1
// S[N,64] = X[N,256] @ W[256,64] -> bf16. blockIdx.y selects branch a/b.
__global__ __launch_bounds__(256) void gemm1(
    const float* __restrict__ X0, const float* __restrict__ X1,
    const float* __restrict__ W0, const float* __restrict__ W1,
    unsigned short* __restrict__ S0, unsigned short* __restrict__ S1, int nN)
{
    const float* X = blockIdx.y ? X1 : X0;
    const float* W = blockIdx.y ? W1 : W0;
    unsigned short* S = blockIdx.y ? S1 : S0;

    __shared__ float Ws[64 * 64]; // 16 KB
    __shared__ float Xs[64 * 64]; // 16 KB
    const int tid = threadIdx.x;
    const int c2 = tid & 31;   // cols {2c2, 2c2+1}
    const int r  = tid >> 5;   // nodes r+8i
    const int n0 = blockIdx.x * 64;

    float acc0[8], acc1[8];
#pragma unroll
    for (int i = 0; i < 8; ++i) { acc0[i] = 0.f; acc1[i] = 0.f; }

    for (int kc = 0; kc < 4; ++kc) {
        __syncthreads();
        const float4* Wg = (const float4*)(W + kc * 4096);
        for (int g = tid; g < 1024; g += 256)
            ((float4*)Ws)[g] = Wg[g];
        for (int g = tid; g < 1024; g += 256) {
            int node = g >> 4, k4 = g & 15;
            int n = n0 + node;
            float4 v = make_float4(0.f, 0.f, 0.f, 0.f);
            if (n < nN) v = ((const float4*)(X + (size_t)n * 256 + kc * 64))[k4];
            ((float4*)Xs)[g] = v;
        }
        __syncthreads();

#pragma unroll
        for (int k8 = 0; k8 < 8; ++k8) {
            const int kb = k8 * 8;
            float2 wreg[8];
#pragma unroll
            for (int kk = 0; kk < 8; ++kk)
                wreg[kk] = *(const float2*)&Ws[(kb + kk) * 64 + 2 * c2];
#pragma unroll
            for (int i = 0; i < 8; ++i) {
                const float* xp = &Xs[(r + 8 * i) * 64 + kb];
                float4 xa = *(const float4*)xp;
                float4 xb = *(const float4*)(xp + 4);
                const float xs[8] = {xa.x, xa.y, xa.z, xa.w, xb.x, xb.y, xb.z, xb.w};
#pragma unroll
                for (int kk = 0; kk < 8; ++kk) {
                    acc0[i] += xs[kk] * wreg[kk].x;
                    acc1[i] += xs[kk] * wreg[kk].y;
                }
            }
        }
    }
#pragma unroll
    for (int i = 0; i < 8; ++i) {
        int n = n0 + r + 8 * i;
        if (n < nN) {
            unsigned int v = (unsigned int)f2bf(acc0[i]) |
                             ((unsigned int)f2bf(acc1[i]) << 16);
            *(unsigned int*)&S[(size_t)n * 64 + 2 * c2] = v;
        }
    }
}

// ---------------------------------------------------------------- layer-1 scatter
__global__ __launch_bounds__(256) void agg_l1(
    const int* __restrict__ src, const int* __restrict__ dst,
    const float* __restrict__ ew,
    const unsigned short* __restrict__ sa, const unsigned short* __restrict__ sb,
    float* __restrict__ aa, float* __restrict__ ab, int nE)
{
    int gid = blockIdx.x * 256 + threadIdx.x;
    int e = gid >> 7;
    int c = gid & 127;
    if (e >= nE) return;
    float w = ew[e];
    int s = src[e], d = dst[e];
    if (c < 64) {
        atomicAdd(&aa[(size_t)d * 64 + c], w * bf2f(sa[(size_t)s * 64 + c]));
    } else {
        c -= 64;
        atomicAdd(&ab[(size_t)d * 64 + c], w * bf2f(sb[(size_t)s * 64 + c]));
    }
}

// ---------------------------------------------------------------- relu + gate1
__global__ __launch_bounds__(256) void relu_gate1(
    const float* __restrict__ aVA, const float* __restrict__ aVB,
    const float* __restrict__ b1a, const float* __restrict__ b1b,
    const float* __restrict__ g1w,
    unsigned short* __restrict__ y1, float* __restrict__ p1, int nN)
{
    const int lane = threadIdx.x & 63;
    const int n = blockIdx.x * 4 + (threadIdx.x >> 6);
    if (n >= nN) return;
    const size_t base = (size_t)n * 64;
    float ya = fmaxf(aVA[base + lane] + b1a[lane], 0.f);
    float yb = fmaxf(aVB[base + lane] + b1b[lane], 0.f);
    y1[(size_t)n * 128 + lane]      = f2bf(ya);
    y1[(size_t)n * 128 + 64 + lane] = f2bf(yb);
    float p = ya * g1w[lane] + yb * g1w[64 + lane];
#pragma unroll
    for (int off = 32; off; off >>= 1) p += __shfl_xor(p, off);
    if (lane == 0) p1[n] = p;
}

// ---------------------------------------------------------------- gate2 + blend
__global__ __launch_bounds__(256) void gate_combine2(
    const float* __restrict__ aVA, const float* __restrict__ aVB,
    const float* __restrict__ b1a, const float* __restrict__ b1b,
    const float* __restrict__ g2w,
    const float* __restrict__ g1b, const float* __restrict__ g2b,
    const unsigned short* __restrict__ y1, const float* __restrict__ p1,
    unsigned short* __restrict__ xbuf, int nN)
{
    const int lane = threadIdx.x & 63;
    const int n = blockIdx.x * 4 + (threadIdx.x >> 6);
    if (n >= nN) return;
    const size_t base = (size_t)n * 64;
    float y2a = fmaxf(aVA[base + lane] + b1a[lane], 0.f);
    float y2b = fmaxf(aVB[base + lane] + b1b[lane], 0.f);
    float p = y2a * g2w[lane] + y2b * g2w[64 + lane];
#pragma unroll
    for (int off = 32; off; off >>= 1) p += __shfl_xor(p, off);
    float lam1 = sigmoidf(p1[n] + g1b[0]);
    float lam2 = sigmoidf(p + g2b[0]);
    float den = fmaxf(lam1 + lam2, 1e-12f);
    float w0 = lam1 / den, w1 = lam2 / den;
    float xlo = w0 * bf2f(y1[(size_t)n * 128 + lane])      + w1 * y2a;
    float xhi = w0 * bf2f(y1[(size_t)n * 128 + 64 + lane]) + w1 * y2b;
    xbuf[(size_t)n * 128 + lane]      = f2bf(xlo);
    xbuf[(size_t)n * 128 + 64 + lane] = f2bf(xhi);
}

// ---------------------------------------------------------------- GEMM2
__global__ __launch_bounds__(256) void gemm2(
    const unsigned short* __restrict__ Xb, const float* __restrict__ W2,
    float* __restrict__ S2, int nN)
{
    __shared__ float W2s[128 * 32]; // 16 KB
    __shared__ float Xs[32 * 128];  // 16 KB
    const int tid = threadIdx.x;
    for (int i = tid; i < 4096; i += 256) W2s[i] = W2[i];
    const int n0 = blockIdx.x * 32;
    for (int g = tid; g < 1024; g += 256) {
        int node = g >> 5, k4 = g & 31;
        int n = n0 + node;
        float4 v = make_float4(0.f, 0.f, 0.f, 0.f);
        if (n < nN) {
            ushort4v u = ((const ushort4v*)(Xb + (size_t)n * 128))[k4];
            v.x = bf2f(u[0]); v.y = bf2f(u[1]); v.z = bf2f(u[2]); v.w = bf2f(u[3]);
        }
        ((float4*)Xs)[g] = v;
    }
    __syncthreads();
    const int j = tid & 31, r = tid >> 5;
    float acc[4] = {0.f, 0.f, 0.f, 0.f};
#pragma unroll 8
    for (int k4 = 0; k4 < 32; ++k4) {
        float w0 = W2s[(k4 * 4 + 0) * 32 + j];
        float w1 = W2s[(k4 * 4 + 1) * 32 + j];
        float w2v = W2s[(k4 * 4 + 2) * 32 + j];
        float w3 = W2s[(k4 * 4 + 3) * 32 + j];
#pragma unroll
        for (int i = 0; i < 4; ++i) {
            float4 xv = ((const float4*)Xs)[(r + (i << 3)) * 32 + k4];
            acc[i] += xv.x * w0 + xv.y * w1 + xv.z * w2v + xv.w * w3;
        }
    }
#pragma unroll
    for (int i = 0; i < 4; ++i) {
        int n = n0 + r + (i << 3);
        if (n < nN) S2[(size_t)n * 32 + j] = acc[i];
    }
}

// ---------------------------------------------------------------- layer-2 scatter
__global__ __launch_bounds__(256) void agg_l2(
    const int* __restrict__ src, const int* __restrict__ dst,
    const float* __restrict__ ew,
    const float* __restrict__ s2, float* __restrict__ agg, int nE)
{
    int gid = blockIdx.x * 256 + threadIdx.x;
    int e = gid >> 5, j = gid & 31;
    if (e >= nE) return;
    atomicAdd(&agg[(size_t)dst[e] * 32 + j], ew[e] * s2[(size_t)src[e] * 32 + j]);
}

// ---------------------------------------------------------------- finalize (f32 out!)
__global__ __launch_bounds__(256) void finalize(
    const float* __restrict__ a1, const float* __restrict__ a2,
    const float* __restrict__ bias2,
    const float* __restrict__ h1w, const float* __restrict__ h1b,
    const float* __restrict__ h2w, const float* __restrict__ h2b,
    float* __restrict__ out, int nN)
{
    const int j = threadIdx.x & 31;
    const int n = blockIdx.x * 8 + (threadIdx.x >> 5);
    if (n >= nN) return;
    float bias = bias2[j];
    float gp1 = a1[(size_t)n * 32 + j] + bias;
    float gp2 = a2[(size_t)n * 32 + j] + bias;
    float p1 = gp1 * h1w[j];
    float p2 = gp2 * h2w[j];
#pragma unroll
    for (int off = 16; off; off >>= 1) {
        p1 += __shfl_xor(p1, off);
        p2 += __shfl_xor(p2, off);
    }
    float mu1 = sigmoidf(p1 + h1b[0]);
    float mu2 = sigmoidf(p2 + h2b[0]);
    float den = fmaxf(mu1 + mu2, 1e-12f);
    float o = (mu1 * gp1 + mu2 * gp2) / den;
    size_t base = (size_t)n * 32 + j;
    out[base] = o;
    out[(size_t)nN * 32 + base] = gp1;
    out[(size_t)2 * nN * 32 + base] = gp2;
}

extern "C" void kernel_launch(void* const* d_in, const int* in_sizes, int n_in,
                              void* d_out, int out_size, void* d_ws, size_t ws_size,
                              hipStream_t stream) {
    const float* x1a = (const float*)d_in[0];
    const float* x1b = (const float*)d_in[1];
    const float* x2a = (const float*)d_in[2];
    const float* x2b = (const float*)d_in[3];
    const int* src1 = (const int*)d_in[4];
    const int* dst1 = (const int*)d_in[5];
    const float* ew1 = (const float*)d_in[6];
    const int* src2 = (const int*)d_in[7];
    const int* dst2 = (const int*)d_in[8];
    const float* ew2 = (const float*)d_in[9];
    const float* W1a = (const float*)d_in[10];
    const float* b1a = (const float*)d_in[11];
    const float* W1b = (const float*)d_in[12];
    const float* b1b = (const float*)d_in[13];
    const float* W2  = (const float*)d_in[14];
    const float* b2  = (const float*)d_in[15];
    const float* g1w = (const float*)d_in[16];
    const float* g1b = (const float*)d_in[17];
    const float* g2w = (const float*)d_in[18];
    const float* g2b = (const float*)d_in[19];
    const float* h1w = (const float*)d_in[20];
    const float* h1b = (const float*)d_in[21];
    const float* h2w = (const float*)d_in[22];
    const float* h2b = (const float*)d_in[23];
    float* out = (float*)d_out;

    const int N = NNODES, E = NEDGES;
    char* base = (char*)d_ws;
    unsigned short* sA = (unsigned short*)(base);             // bf16 [N,64]
    unsigned short* sB = (unsigned short*)(base + 6400000);   // bf16 [N,64]
    unsigned short* y1 = (unsigned short*)(base + 12800000);  // bf16 [N,128]
    float* aVA = (float*)(base + 25600000);                   // f32 [N,64]
    float* aVB = (float*)(base + 38400000);                   // f32 [N,64]
    float* p1  = (float*)(base + 51200000);                   // f32 [N]
    // phase-2 overlays
    unsigned short* xbuf = sA;                                // bf16 [N,128]
    float* s2    = (float*)(base + 12800000);                 // f32 [N,32]
    float* aL2_1 = (float*)(base + 25600000);                 // f32 [N,32]
    float* aL2_2 = (float*)(base + 32000000);                 // f32 [N,32]

    if (ws_size < (size_t)51200000 + (size_t)N * 4) return;   // diagnostic guard

    const dim3 gemmGrid((N + 63) / 64, 2);
    const int agg1Blocks = (E * 128) / 256;  // 400000
    const int agg2Blocks = (E * 32) / 256;   // 100000

    // view 1
    hipMemsetAsync(aVA, 0, 25600000, stream);
    gemm1<<<gemmGrid, 256, 0, stream>>>(x1a, x1b, W1a, W1b, sA, sB, N);
    agg_l1<<<agg1Blocks, 256, 0, stream>>>(src1, dst1, ew1, sA, sB, aVA, aVB, E);
    relu_gate1<<<(N + 3) / 4, 256, 0, stream>>>(aVA, aVB, b1a, b1b, g1w, y1, p1, N);
    // view 2 (shared W1a/W1b)
    hipMemsetAsync(aVA, 0, 25600000, stream);
    gemm1<<<gemmGrid, 256, 0, stream>>>(x2a, x2b, W1a, W1b, sA, sB, N);
    agg_l1<<<agg1Blocks, 256, 0, stream>>>(src2, dst2, ew2, sA, sB, aVA, aVB, E);
    gate_combine2<<<(N + 3) / 4, 256, 0, stream>>>(aVA, aVB, b1a, b1b, g2w, g1b, g2b,
                                                   y1, p1, xbuf, N);
    // second layer
    gemm2<<<(N + 31) / 32, 256, 0, stream>>>(xbuf, W2, s2, N);
    hipMemsetAsync(aL2_1, 0, 12800000, stream);
    agg_l2<<<agg2Blocks, 256, 0, stream>>>(src1, dst1, ew1, s2, aL2_1, E);
    agg_l2<<<agg2Blocks, 256, 0, stream>>>(src2, dst2, ew2, s2, aL2_2, E);
    // finalize
    finalize<<<(N + 7) / 8, 256, 0, stream>>>(aL2_1, aL2_2, b2,
                                              h1w, h1b, h2w, h2b, out, N);
}

// Round 6
// 957.612 us; speedup vs baseline: 1.4078x; 1.4078x over previous
//
#include <hip/hip_runtime.h>
#include <hip/hip_bf16.h>

// DaGCN forward, CSR-gather version (no f32 atomics).
// Inputs f32 + int32; OUTPUT f32 (3 x [N,32] concat).
//
// Per call: build CSR for both graphs (hist -> scan -> fill, int atomics only),
// then: gemm1 x4 (one launch) -> fused_l1 (gather+relu+gates+blend) -> gemm2
// -> fused_l2 (gather both graphs + final gates, writes all 3 outputs).
//
// Workspace (byte offsets):
//   [0, 6.4M)        s1A bf16 [N,64]   (phase2 overlay: s2bf bf16 [N,32])
//   [6.4M, 12.8M)    s1B
//   [12.8M, 19.2M)   s2A
//   [19.2M, 25.6M)   s2B
//   [25.6M, 38.4M)   xbuf bf16 [N,128]
//   [38.4M, 38.6M)   rs1 int[N+1]
//   [38.6M, 38.8M)   rs2 int[N+1]
//   [38.81M, 39.01M) cur1 int[N]   (hist counts, then fill cursors)
//   [39.01M, 39.21M) cur2 int[N]
//   [39.21M, 42.4M)  eid1 int[E]
//   [42.4M, 45.6M)   eid2 int[E]
// Peak 45.6 MB (guard 51.4MB known to pass).

#define NNODES 50000
#define NEDGES 800000

__device__ __forceinline__ float bf2f(unsigned short u) {
    return __uint_as_float(((unsigned int)u) << 16);
}
__device__ __forceinline__ unsigned short f2bf(float f) {
    __hip_bfloat16 h = __float2bfloat16(f);
    unsigned short u;
    __builtin_memcpy(&u, &h, 2);
    return u;
}
__device__ __forceinline__ float sigmoidf(float v) {
    return 1.f / (1.f + expf(-v));
}

// ---------------------------------------------------------------- CSR build
__global__ __launch_bounds__(256) void hist(
    const int* __restrict__ dst1, const int* __restrict__ dst2,
    int* __restrict__ c1, int* __restrict__ c2, int nE)
{
    const int* dst = blockIdx.y ? dst2 : dst1;
    int* cnt = blockIdx.y ? c2 : c1;
    int e = blockIdx.x * 256 + threadIdx.x;
    if (e < nE) atomicAdd(&cnt[dst[e]], 1);
}

// One block per graph. counts (=cur) -> rowstart + exclusive cursors in-place.
__global__ __launch_bounds__(1024) void scan_csr(
    const int* c1, const int* c2, int* rs1, int* rs2, int* cur1, int* cur2, int nN)
{
    const int g = blockIdx.x;
    const int* cnt = g ? c2 : c1;
    int* rs = g ? rs2 : rs1;
    int* cur = g ? cur2 : cur1;
    __shared__ int sd[1024];
    const int tid = threadIdx.x;
    const int SEG = 49; // 1024*49 = 50176 >= N
    const int base = tid * SEG;
    int local = 0;
    for (int i = 0; i < SEG; ++i) {
        int idx = base + i;
        if (idx < nN) local += cnt[idx];
    }
    sd[tid] = local;
    __syncthreads();
    for (int off = 1; off < 1024; off <<= 1) {
        int v = (tid >= off) ? sd[tid - off] : 0;
        __syncthreads();
        sd[tid] += v;
        __syncthreads();
    }
    int run = sd[tid] - local; // exclusive prefix of this thread's segment
    for (int i = 0; i < SEG; ++i) {
        int idx = base + i;
        if (idx < nN) {
            int c = cnt[idx];   // read BEFORE overwrite (cnt aliases cur)
            rs[idx] = run;
            cur[idx] = run;
            run += c;
        }
    }
    if (tid == 1023) rs[nN] = sd[1023];
}

__global__ __launch_bounds__(256) void fill_csr(
    const int* __restrict__ dst1, const int* __restrict__ dst2,
    int* __restrict__ cur1, int* __restrict__ cur2,
    int* __restrict__ eid1, int* __restrict__ eid2, int nE)
{
    const int* dst = blockIdx.y ? dst2 : dst1;
    int* cur = blockIdx.y ? cur2 : cur1;
    int* eid = blockIdx.y ? eid2 : eid1;
    int e = blockIdx.x * 256 + threadIdx.x;
    if (e < nE) {
        int pos = atomicAdd(&cur[dst[e]], 1);
        eid[pos] = e;
    }
}

// ---------------------------------------------------------------- GEMM1 (x4)
// blockIdx.y in 0..3 selects (X, W, S): {x1a,W1a,s1A},{x1b,W1b,s1B},{x2a,W1a,s2A},{x2b,W1b,s2B}
__global__ __launch_bounds__(256) void gemm1(
    const float* __restrict__ Xa, const float* __restrict__ Xb,
    const float* __restrict__ Xc, const float* __restrict__ Xd,
    const float* __restrict__ Wa, const float* __restrict__ Wb,
    unsigned short* __restrict__ Sa, unsigned short* __restrict__ Sb,
    unsigned short* __restrict__ Sc, unsigned short* __restrict__ Sd, int nN)
{
    const int by = blockIdx.y;
    const float* X = (by == 0) ? Xa : (by == 1) ? Xb : (by == 2) ? Xc : Xd;
    const float* W = (by & 1) ? Wb : Wa;
    unsigned short* S = (by == 0) ? Sa : (by == 1) ? Sb : (by == 2) ? Sc : Sd;

    __shared__ float Ws[64 * 64]; // 16 KB
    __shared__ float Xs[64 * 64]; // 16 KB
    const int tid = threadIdx.x;
    const int c2 = tid & 31;
    const int r  = tid >> 5;
    const int n0 = blockIdx.x * 64;

    float acc0[8], acc1[8];
#pragma unroll
    for (int i = 0; i < 8; ++i) { acc0[i] = 0.f; acc1[i] = 0.f; }

    for (int kc = 0; kc < 4; ++kc) {
        __syncthreads();
        const float4* Wg = (const float4*)(W + kc * 4096);
        for (int g = tid; g < 1024; g += 256)
            ((float4*)Ws)[g] = Wg[g];
        for (int g = tid; g < 1024; g += 256) {
            int node = g >> 4, k4 = g & 15;
            int n = n0 + node;
            float4 v = make_float4(0.f, 0.f, 0.f, 0.f);
            if (n < nN) v = ((const float4*)(X + (size_t)n * 256 + kc * 64))[k4];
            ((float4*)Xs)[g] = v;
        }
        __syncthreads();

#pragma unroll
        for (int k8 = 0; k8 < 8; ++k8) {
            const int kb = k8 * 8;
            float2 wreg[8];
#pragma unroll
            for (int kk = 0; kk < 8; ++kk)
                wreg[kk] = *(const float2*)&Ws[(kb + kk) * 64 + 2 * c2];
#pragma unroll
            for (int i = 0; i < 8; ++i) {
                const float* xp = &Xs[(r + 8 * i) * 64 + kb];
                float4 xa = *(const float4*)xp;
                float4 xb = *(const float4*)(xp + 4);
                const float xs[8] = {xa.x, xa.y, xa.z, xa.w, xb.x, xb.y, xb.z, xb.w};
#pragma unroll
                for (int kk = 0; kk < 8; ++kk) {
                    acc0[i] += xs[kk] * wreg[kk].x;
                    acc1[i] += xs[kk] * wreg[kk].y;
                }
            }
        }
    }
#pragma unroll
    for (int i = 0; i < 8; ++i) {
        int n = n0 + r + 8 * i;
        if (n < nN) {
            unsigned int v = (unsigned int)f2bf(acc0[i]) |
                             ((unsigned int)f2bf(acc1[i]) << 16);
            *(unsigned int*)&S[(size_t)n * 64 + 2 * c2] = v;
        }
    }
}

// ---------------------------------------------------------------- fused layer-1
// One wave per node. Gather both views' aggregates, relu+bias, sigmoid gates,
// L1-normalized blend -> xbuf bf16 [N,128].
__global__ __launch_bounds__(256) void fused_l1(
    const int* __restrict__ rs1, const int* __restrict__ eid1,
    const int* __restrict__ src1, const float* __restrict__ ew1,
    const int* __restrict__ rs2, const int* __restrict__ eid2,
    const int* __restrict__ src2, const float* __restrict__ ew2,
    const unsigned short* __restrict__ s1A, const unsigned short* __restrict__ s1B,
    const unsigned short* __restrict__ s2A, const unsigned short* __restrict__ s2B,
    const float* __restrict__ b1a, const float* __restrict__ b1b,
    const float* __restrict__ g1w, const float* __restrict__ g1b,
    const float* __restrict__ g2w, const float* __restrict__ g2b,
    unsigned short* __restrict__ xbuf, int nN)
{
    const int c = threadIdx.x & 63;
    const int n = blockIdx.x * 4 + (threadIdx.x >> 6);
    if (n >= nN) return;

    float a1 = 0.f, bb1 = 0.f, a2 = 0.f, bb2 = 0.f;
    // view 1
    {
        int i = rs1[n], e = rs1[n + 1];
        for (; i + 1 < e; i += 2) {
            int id0 = eid1[i], id1 = eid1[i + 1];
            int s0 = src1[id0], s1 = src1[id1];
            float w0 = ew1[id0], w1 = ew1[id1];
            float r0a = bf2f(s1A[(size_t)s0 * 64 + c]);
            float r0b = bf2f(s1B[(size_t)s0 * 64 + c]);
            float r1a = bf2f(s1A[(size_t)s1 * 64 + c]);
            float r1b = bf2f(s1B[(size_t)s1 * 64 + c]);
            a1 += w0 * r0a; bb1 += w0 * r0b;
            a1 += w1 * r1a; bb1 += w1 * r1b;
        }
        if (i < e) {
            int id = eid1[i];
            int s = src1[id];
            float w = ew1[id];
            a1 += w * bf2f(s1A[(size_t)s * 64 + c]);
            bb1 += w * bf2f(s1B[(size_t)s * 64 + c]);
        }
    }
    // view 2
    {
        int i = rs2[n], e = rs2[n + 1];
        for (; i + 1 < e; i += 2) {
            int id0 = eid2[i], id1 = eid2[i + 1];
            int s0 = src2[id0], s1 = src2[id1];
            float w0 = ew2[id0], w1 = ew2[id1];
            float r0a = bf2f(s2A[(size_t)s0 * 64 + c]);
            float r0b = bf2f(s2B[(size_t)s0 * 64 + c]);
            float r1a = bf2f(s2A[(size_t)s1 * 64 + c]);
            float r1b = bf2f(s2B[(size_t)s1 * 64 + c]);
            a2 += w0 * r0a; bb2 += w0 * r0b;
            a2 += w1 * r1a; bb2 += w1 * r1b;
        }
        if (i < e) {
            int id = eid2[i];
            int s = src2[id];
            float w = ew2[id];
            a2 += w * bf2f(s2A[(size_t)s * 64 + c]);
            bb2 += w * bf2f(s2B[(size_t)s * 64 + c]);
        }
    }

    float x1l = fmaxf(a1 + b1a[c], 0.f);
    float x1h = fmaxf(bb1 + b1b[c], 0.f);
    float x2l = fmaxf(a2 + b1a[c], 0.f);
    float x2h = fmaxf(bb2 + b1b[c], 0.f);
    float p1 = x1l * g1w[c] + x1h * g1w[64 + c];
    float p2 = x2l * g2w[c] + x2h * g2w[64 + c];
#pragma unroll
    for (int off = 32; off; off >>= 1) {
        p1 += __shfl_xor(p1, off);
        p2 += __shfl_xor(p2, off);
    }
    float lam1 = sigmoidf(p1 + g1b[0]);
    float lam2 = sigmoidf(p2 + g2b[0]);
    float den = fmaxf(lam1 + lam2, 1e-12f);
    float w0 = lam1 / den, w1 = lam2 / den;
    xbuf[(size_t)n * 128 + c]      = f2bf(w0 * x1l + w1 * x2l);
    xbuf[(size_t)n * 128 + 64 + c] = f2bf(w0 * x1h + w1 * x2h);
}

// ---------------------------------------------------------------- GEMM2 -> bf16
__global__ __launch_bounds__(256) void gemm2(
    const unsigned short* __restrict__ Xb, const float* __restrict__ W2,
    unsigned short* __restrict__ S2, int nN)
{
    __shared__ float W2s[128 * 32]; // 16 KB
    __shared__ float Xs[32 * 128];  // 16 KB
    const int tid = threadIdx.x;
    for (int i = tid; i < 4096; i += 256) W2s[i] = W2[i];
    const int n0 = blockIdx.x * 32;
    for (int g = tid; g < 1024; g += 256) {
        int node = g >> 5, k4 = g & 31;
        int n = n0 + node;
        float4 v = make_float4(0.f, 0.f, 0.f, 0.f);
        if (n < nN) {
            const unsigned short* xp = Xb + (size_t)n * 128 + k4 * 4;
            v.x = bf2f(xp[0]); v.y = bf2f(xp[1]); v.z = bf2f(xp[2]); v.w = bf2f(xp[3]);
        }
        ((float4*)Xs)[g] = v;
    }
    __syncthreads();
    const int j = tid & 31, r = tid >> 5;
    float acc[4] = {0.f, 0.f, 0.f, 0.f};
#pragma unroll 8
    for (int k4 = 0; k4 < 32; ++k4) {
        float w0 = W2s[(k4 * 4 + 0) * 32 + j];
        float w1 = W2s[(k4 * 4 + 1) * 32 + j];
        float w2v = W2s[(k4 * 4 + 2) * 32 + j];
        float w3 = W2s[(k4 * 4 + 3) * 32 + j];
#pragma unroll
        for (int i = 0; i < 4; ++i) {
            float4 xv = ((const float4*)Xs)[(r + (i << 3)) * 32 + k4];
            acc[i] += xv.x * w0 + xv.y * w1 + xv.z * w2v + xv.w * w3;
        }
    }
#pragma unroll
    for (int i = 0; i < 4; ++i) {
        int n = n0 + r + (i << 3);
        if (n < nN) S2[(size_t)n * 32 + j] = f2bf(acc[i]);
    }
}

// ---------------------------------------------------------------- fused layer-2
// One wave per node: lanes 0-31 aggregate graph1, lanes 32-63 graph2.
// Then gates + blend; writes all three f32 outputs.
__global__ __launch_bounds__(256) void fused_l2(
    const int* __restrict__ rs1, const int* __restrict__ eid1,
    const int* __restrict__ src1, const float* __restrict__ ew1,
    const int* __restrict__ rs2, const int* __restrict__ eid2,
    const int* __restrict__ src2, const float* __restrict__ ew2,
    const unsigned short* __restrict__ s2bf, const float* __restrict__ bias2,
    const float* __restrict__ h1w, const float* __restrict__ h1b,
    const float* __restrict__ h2w, const float* __restrict__ h2b,
    float* __restrict__ out, int nN)
{
    const int lane = threadIdx.x & 63;
    const int n = blockIdx.x * 4 + (threadIdx.x >> 6);
    if (n >= nN) return;
    const int half = lane >> 5;
    const int j = lane & 31;

    const int* rs = half ? rs2 : rs1;
    const int* eid = half ? eid2 : eid1;
    const int* srcA = half ? src2 : src1;
    const float* ewA = half ? ew2 : ew1;

    float acc = 0.f;
    {
        int i = rs[n], e = rs[n + 1];
        for (; i + 1 < e; i += 2) {
            int id0 = eid[i], id1 = eid[i + 1];
            int s0 = srcA[id0], s1 = srcA[id1];
            float w0 = ewA[id0], w1 = ewA[id1];
            float r0 = bf2f(s2bf[(size_t)s0 * 32 + j]);
            float r1 = bf2f(s2bf[(size_t)s1 * 32 + j]);
            acc += w0 * r0;
            acc += w1 * r1;
        }
        if (i < e) {
            int id = eid[i];
            acc += ewA[id] * bf2f(s2bf[(size_t)srcA[id] * 32 + j]);
        }
    }
    float gp = acc + bias2[j];
    float p = gp * (half ? h2w[j] : h1w[j]);
#pragma unroll
    for (int off = 16; off; off >>= 1) p += __shfl_xor(p, off);
    float pO = __shfl_xor(p, 32);
    float pp1 = half ? pO : p;
    float pp2 = half ? p : pO;
    float mu1 = sigmoidf(pp1 + h1b[0]);
    float mu2 = sigmoidf(pp2 + h2b[0]);
    float den = fmaxf(mu1 + mu2, 1e-12f);
    float gpO = __shfl_xor(gp, 32);
    size_t base = (size_t)n * 32 + j;
    if (half == 0) {
        out[base] = (mu1 * gp + mu2 * gpO) / den;
        out[(size_t)nN * 32 + base] = gp;
    } else {
        out[(size_t)2 * nN * 32 + base] = gp;
    }
}

extern "C" void kernel_launch(void* const* d_in, const int* in_sizes, int n_in,
                              void* d_out, int out_size, void* d_ws, size_t ws_size,
                              hipStream_t stream) {
    const float* x1a = (const float*)d_in[0];
    const float* x1b = (const float*)d_in[1];
    const float* x2a = (const float*)d_in[2];
    const float* x2b = (const float*)d_in[3];
    const int* src1 = (const int*)d_in[4];
    const int* dst1 = (const int*)d_in[5];
    const float* ew1 = (const float*)d_in[6];
    const int* src2 = (const int*)d_in[7];
    const int* dst2 = (const int*)d_in[8];
    const float* ew2 = (const float*)d_in[9];
    const float* W1a = (const float*)d_in[10];
    const float* b1a = (const float*)d_in[11];
    const float* W1b = (const float*)d_in[12];
    const float* b1b = (const float*)d_in[13];
    const float* W2  = (const float*)d_in[14];
    const float* b2  = (const float*)d_in[15];
    const float* g1w = (const float*)d_in[16];
    const float* g1b = (const float*)d_in[17];
    const float* g2w = (const float*)d_in[18];
    const float* g2b = (const float*)d_in[19];
    const float* h1w = (const float*)d_in[20];
    const float* h1b = (const float*)d_in[21];
    const float* h2w = (const float*)d_in[22];
    const float* h2b = (const float*)d_in[23];
    float* out = (float*)d_out;

    const int N = NNODES, E = NEDGES;
    char* base = (char*)d_ws;
    unsigned short* s1A = (unsigned short*)(base);
    unsigned short* s1B = (unsigned short*)(base + 6400000);
    unsigned short* s2A = (unsigned short*)(base + 12800000);
    unsigned short* s2B = (unsigned short*)(base + 19200000);
    unsigned short* xbuf = (unsigned short*)(base + 25600000);
    int* rs1  = (int*)(base + 38400000);
    int* rs2  = (int*)(base + 38604800);
    int* cur1 = (int*)(base + 38809600);
    int* cur2 = (int*)(base + 39009600);
    int* eid1 = (int*)(base + 39209600);
    int* eid2 = (int*)(base + 42409600);
    unsigned short* s2bf = s1A; // overlay after fused_l1

    if (ws_size < (size_t)51400000) return; // guard (known to pass)

    const int eBlocks = (E + 255) / 256; // 3125

    // CSR build for both graphs
    hipMemsetAsync(cur1, 0, 400000, stream); // cur1+cur2 contiguous
    hist<<<dim3(eBlocks, 2), 256, 0, stream>>>(dst1, dst2, cur1, cur2, E);
    scan_csr<<<2, 1024, 0, stream>>>(cur1, cur2, rs1, rs2, cur1, cur2, N);
    fill_csr<<<dim3(eBlocks, 2), 256, 0, stream>>>(dst1, dst2, cur1, cur2, eid1, eid2, E);

    // layer 1 dense
    gemm1<<<dim3((N + 63) / 64, 4), 256, 0, stream>>>(
        x1a, x1b, x2a, x2b, W1a, W1b, s1A, s1B, s2A, s2B, N);
    // fused gather + gates -> xbuf
    fused_l1<<<(N + 3) / 4, 256, 0, stream>>>(
        rs1, eid1, src1, ew1, rs2, eid2, src2, ew2,
        s1A, s1B, s2A, s2B, b1a, b1b, g1w, g1b, g2w, g2b, xbuf, N);
    // layer 2 dense
    gemm2<<<(N + 31) / 32, 256, 0, stream>>>(xbuf, W2, s2bf, N);
    // fused gather + final gates -> out
    fused_l2<<<(N + 3) / 4, 256, 0, stream>>>(
        rs1, eid1, src1, ew1, rs2, eid2, src2, ew2,
        s2bf, b2, h1w, h1b, h2w, h2b, out, N);
}